// Round 8
// baseline (1469.428 us; speedup 1.0000x reference)
//
#include <hip/hip_runtime.h>
#include <stdint.h>

// NARM fused pipeline v12 for MI355X (gfx950).
//   v11 post-mortem: three rounds pinned at ~399us. Scan per-step 1.11us survived
//   5 structural attacks with NO pipe saturated (Mfma 12.6 / VALU 19 / HBM 10%)
//   -> phase-serialized latency chain; 128 blocks on 256 CUs never co-locate, so
//   the m114 wave-overlap mechanism (waves at DIFFERENT phases share a CU's
//   MFMA+VALU pipes) has never been active.
//   v12 = split-phase scan: 64 blocks x 1024 thr; each block = TWO independent
//   16-row GRU recurrences (halves) on one CU. Each half has its own LDS buffers
//   and a per-half LDS-flag barrier (monotonic counter; lane0 atomicAdd + spin)
//   instead of block-wide s_barrier -> halves slide in phase; one-time s_sleep
//   on half 1 seeds ~half-step anti-phase. MFMA of one half overlaps VALU of the
//   other.
//   Launches: k_build (stash); L1 scan2(0..99); L2 scan2(100..199)+sccum(0);
//   L3 sccum(1). sccum = v11's fused score+cumsum (passed), adapted to 1024 thr
//   (two 512-thr instances per block).

typedef __attribute__((ext_vector_type(8))) short short8;
typedef __attribute__((ext_vector_type(4))) float float4v;

__device__ inline float bf2f(unsigned short u){
  union { unsigned int i; float f; } v; v.i = ((unsigned int)u) << 16; return v.f;
}
__device__ inline unsigned short f2bf(float f){
  union { float f; unsigned int i; } v; v.f = f;
  unsigned int x = v.i;
  return (unsigned short)((x + 0x7fffu + ((x >> 16) & 1u)) >> 16);
}
// HW packed f32->bf16 RNE (identical rounding to f2bf); no builtin on gfx950
__device__ inline unsigned int cvt_pk_bf16(float a, float b){
  unsigned int r;
  asm("v_cvt_pk_bf16_f32 %0, %1, %2" : "=v"(r) : "v"(a), "v"(b));
  return r;
}
__device__ inline float sigm(float x){ return __builtin_amdgcn_rcpf(1.0f + __expf(-x)); }

// ---------------- builder: bf16 weight stash + bf16 A1|A2 ----------------
// wst layout: fragment f=(gm*3+G)*4+kf (gm: 0=Wih_g 1=Whh_g 2=Wih_l 3=Whh_l);
// element i=(f<<12)|(t<<3)|e = bf16(src[(G*128+(t>>6)*16+(t&15))*128 + (f&3)*32
// + ((t>>4)&3)*8 + e]) so scan thread t loads fragment (G,kf) as one 16B read.
__global__ __launch_bounds__(512) void k_build(
    const float* __restrict__ Wih_g, const float* __restrict__ Whh_g,
    const float* __restrict__ Wih_l, const float* __restrict__ Whh_l,
    const float* __restrict__ A1, const float* __restrict__ A2,
    unsigned short* __restrict__ wst, unsigned short* __restrict__ a12)
{
  int gid = blockIdx.x * 512 + threadIdx.x;     // grid 128 -> 65536 threads
  if (gid < 32768) a12[gid] = f2bf((gid < 16384) ? A1[gid] : A2[gid - 16384]);
  #pragma unroll
  for (int k = 0; k < 3; k++) {
    int i = gid + k * 65536;                    // 0..196607
    int f = i >> 12;                            // 0..47
    int r = i & 4095;
    int t = r >> 3, e = r & 7;
    int l15 = t & 15, q = (t >> 4) & 3, wv = t >> 6;
    int col = wv * 16 + l15;
    int kf = f & 3, g3 = f >> 2;                // g3 = gm*3+G
    int G = g3 % 3, gm = g3 / 3;
    const float* src = (gm == 0) ? Wih_g : (gm == 1) ? Whh_g : (gm == 2) ? Wih_l : Whh_l;
    int row = G * 128 + col;
    int kk = kf * 32 + q * 8 + e;
    wst[i] = f2bf(src[(size_t)row * 128 + kk]);
  }
}

// ---------------- fat kernel: scan2 | sccum roles ----------------
union __align__(16) LdsU {
  struct {
    unsigned short hbuf[2][2][16][136];   // [half][pp][row][col]
    unsigned short xbuf[2][2][16][136];
    unsigned bar[2];                      // per-half monotonic barrier counter
  } scan;                                 // 34,824 B
  struct CmI {
    unsigned short hlL[25 * 544];         // [sl][b4*136 + j]
    unsigned short hgL[25 * 544];
    float part[8 * 112];
    float scR[112];
  } cm[2];                                // 116,864 B
};

__global__ __launch_bounds__(1024, 1) void k_fat(
    const float* __restrict__ x,
    const float* __restrict__ bih_g, const float* __restrict__ bhh_g,
    const float* __restrict__ bih_l, const float* __restrict__ bhh_l,
    const unsigned short* __restrict__ wst, const unsigned short* __restrict__ a12,
    const float* __restrict__ v1, const int* __restrict__ lengths,
    unsigned short* __restrict__ hl, unsigned short* __restrict__ hg,
    float* __restrict__ cum, float* __restrict__ out,
    int scan_t0, int sccum_t0, int sccum_base)
{
  __shared__ LdsU lds;
  int tid = threadIdx.x;
  int bid = blockIdx.x;

  if (scan_t0 >= 0 && bid < 64) {
    // ========== scan2 role: two independent halves, chunk [t0, t0+100) ==========
    const int tc = 100;
    int t0 = scan_t0;
    int t = tid & 511, half = tid >> 9;
    unsigned short (&hbuf)[2][16][136] = lds.scan.hbuf[half];
    unsigned short (&xbuf)[2][16][136] = lds.scan.xbuf[half];
    volatile unsigned* bp = &lds.scan.bar[half];

    int w = t >> 6, L = t & 63, l15 = L & 15, q = L >> 4;
    int gru = bid & 1;                   // 0 = g, 1 = l
    int b0 = ((bid >> 1) * 2 + half) * 16;
    const float* bih = gru ? bih_l : bih_g;
    const float* bhh = gru ? bhh_l : bhh_g;
    unsigned short* myseq = gru ? hl : hg;

    int col = w * 16 + l15;

    // weight B-fragments from bf16 stash (k_build ran in a prior launch)
    short8 Wi[3][4], Wh[3][4];
    {
      int gmi = gru * 2, gmh = gru * 2 + 1;
      #pragma unroll
      for (int G = 0; G < 3; G++) {
        #pragma unroll
        for (int kf = 0; kf < 4; kf++) {
          Wi[G][kf] = *(const short8*)(wst + (((size_t)((gmi * 3 + G) * 4 + kf)) << 12) + t * 8);
          Wh[G][kf] = *(const short8*)(wst + (((size_t)((gmh * 3 + G) * 4 + kf)) << 12) + t * 8);
        }
      }
    }
    float br  = bih[col]       + bhh[col];
    float bz  = bih[128 + col] + bhh[128 + col];
    float bin = bih[256 + col];             // bhh_n stays inside r*( ) per PyTorch GRU
    float bnh = bhh[256 + col];

    // init h: zeros for chunk 0, else previous chunk's last slice
    float hold[4];
    if (t0 == 0) {
      #pragma unroll
      for (int r = 0; r < 4; r++) { hold[r] = 0.0f; hbuf[0][q * 4 + r][col] = 0; }
    } else {
      const unsigned short* carry = myseq + (size_t)(t0 - 1) * 131072;
      #pragma unroll
      for (int r = 0; r < 4; r++) {
        int m = q * 4 + r;
        unsigned short u = carry[(size_t)(b0 + m) * 128 + col];
        hold[r] = bf2f(u);
        hbuf[0][m][col] = u;
      }
    }
    // stage x(t0) into xbuf[0]; prefetch x(t0+1)
    int xrow = t >> 5, xc4 = (t & 31) * 4;
    size_t hoff = (size_t)b0 * 128 + xrow * 128 + xc4;
    {
      float4 x0 = ((const float4*)(x + ((size_t)t0 * 1024 + b0) * 128))[t];
      *(uint2*)&xbuf[0][xrow][xc4] = make_uint2(cvt_pk_bf16(x0.x, x0.y), cvt_pk_bf16(x0.z, x0.w));
    }
    float4 xr = ((const float4*)(x + ((size_t)(t0 + 1) * 1024 + b0) * 128))[t];

    if (tid < 2) lds.scan.bar[tid] = 0;
    __syncthreads();                       // block-wide once; halves diverge after

    // seed anti-phase: half 1 sleeps ~960 cycles (~half a step)
    if (half) __builtin_amdgcn_s_sleep(15);

    unsigned barcnt = 0;
    auto half_bar = [&]() {
      barcnt += 8;
      asm volatile("s_waitcnt lgkmcnt(0)" ::: "memory");  // my LDS writes done
      if (L == 0) atomicAdd((unsigned*)&lds.scan.bar[half], 1u);
      while (*bp < barcnt) { }
      __builtin_amdgcn_sched_barrier(0);
      asm volatile("" ::: "memory");
    };

    // prologue: x-side chains for step 0
    float4v cx0 = (float4v){0.f,0.f,0.f,0.f}, cx1 = cx0, cx2 = cx0;
    {
      short8 Ax[4];
      #pragma unroll
      for (int kf = 0; kf < 4; kf++) Ax[kf] = *(const short8*)&xbuf[0][l15][kf * 32 + q * 8];
      #pragma unroll
      for (int kf = 0; kf < 4; kf++) cx0 = __builtin_amdgcn_mfma_f32_16x16x32_bf16(Ax[kf], Wi[0][kf], cx0, 0,0,0);
      #pragma unroll
      for (int kf = 0; kf < 4; kf++) cx1 = __builtin_amdgcn_mfma_f32_16x16x32_bf16(Ax[kf], Wi[1][kf], cx1, 0,0,0);
      #pragma unroll
      for (int kf = 0; kf < 4; kf++) cx2 = __builtin_amdgcn_mfma_f32_16x16x32_bf16(Ax[kf], Wi[2][kf], cx2, 0,0,0);
    }
    *(uint2*)&xbuf[1][xrow][xc4] = make_uint2(cvt_pk_bf16(xr.x, xr.y), cvt_pk_bf16(xr.z, xr.w));
    xr = ((const float4*)(x + ((size_t)(t0 + 2) * 1024 + b0) * 128))[t];
    half_bar();

    auto step = [&](int s, int pin, int pout) {
      short8 Ah[4], Axn[4];
      #pragma unroll
      for (int kf = 0; kf < 4; kf++) Ah[kf]  = *(const short8*)&hbuf[pin][l15][kf * 32 + q * 8];
      #pragma unroll
      for (int kf = 0; kf < 4; kf++) Axn[kf] = *(const short8*)&xbuf[pout][l15][kf * 32 + q * 8];

      if (s > 0) {
        uint2 hv = *(const uint2*)&hbuf[pin][xrow][xc4];
        *(uint2*)(myseq + (size_t)(t0 + s - 1) * 131072 + hoff) = hv;
      }

      // critical-path h-chains first
      float4v rh = (float4v){0.f,0.f,0.f,0.f}, zh = rh, nh = rh;
      #pragma unroll
      for (int kf = 0; kf < 4; kf++) rh = __builtin_amdgcn_mfma_f32_16x16x32_bf16(Ah[kf], Wh[0][kf], rh, 0,0,0);
      #pragma unroll
      for (int kf = 0; kf < 4; kf++) zh = __builtin_amdgcn_mfma_f32_16x16x32_bf16(Ah[kf], Wh[1][kf], zh, 0,0,0);
      #pragma unroll
      for (int kf = 0; kf < 4; kf++) nh = __builtin_amdgcn_mfma_f32_16x16x32_bf16(Ah[kf], Wh[2][kf], nh, 0,0,0);

      // background x-chains for step s+1 (drain during gate phase)
      float4v nx0 = (float4v){0.f,0.f,0.f,0.f}, nx1 = nx0, nx2 = nx0;
      #pragma unroll
      for (int kf = 0; kf < 4; kf++) nx0 = __builtin_amdgcn_mfma_f32_16x16x32_bf16(Axn[kf], Wi[0][kf], nx0, 0,0,0);
      #pragma unroll
      for (int kf = 0; kf < 4; kf++) nx1 = __builtin_amdgcn_mfma_f32_16x16x32_bf16(Axn[kf], Wi[1][kf], nx1, 0,0,0);
      #pragma unroll
      for (int kf = 0; kf < 4; kf++) nx2 = __builtin_amdgcn_mfma_f32_16x16x32_bf16(Axn[kf], Wi[2][kf], nx2, 0,0,0);

      // commit prefetched x(s+2) into dead buffer; prefetch x(s+3)
      *(uint2*)&xbuf[pin][xrow][xc4] = make_uint2(cvt_pk_bf16(xr.x, xr.y), cvt_pk_bf16(xr.z, xr.w));
      {
        int t3 = t0 + (s + 3 < tc ? s + 3 : tc - 1);
        xr = ((const float4*)(x + ((size_t)t3 * 1024 + b0) * 128))[t];
      }

      float cr[4], cz[4], cn[4];
      #pragma unroll
      for (int r = 0; r < 4; r++) { cr[r] = cx0[r] + br; cz[r] = cx1[r] + bz; cn[r] = cx2[r] + bin; }

      float hnv[4];
      #pragma unroll
      for (int r = 0; r < 4; r++) {
        float er = __expf(-(rh[r] + cr[r]));
        float ez = __expf(-(zh[r] + cz[r]));
        float pr = 1.0f + er, pz = 1.0f + ez;
        float inv = __builtin_amdgcn_rcpf(pr * pz);
        float rr = pz * inv;                  // = 1/(1+er)
        float zz = pr * inv;                  // = 1/(1+ez)
        float y  = cn[r] + rr * (nh[r] + bnh);
        float em = __expf(-2.0f * y);
        float nn = 2.0f * __builtin_amdgcn_rcpf(1.0f + em) - 1.0f;   // tanh(y)
        hnv[r] = nn + zz * (hold[r] - nn);
        hold[r] = hnv[r];
      }
      unsigned int p01 = cvt_pk_bf16(hnv[0], hnv[1]);
      unsigned int p23 = cvt_pk_bf16(hnv[2], hnv[3]);
      hbuf[pout][q * 4 + 0][col] = (unsigned short)p01;
      hbuf[pout][q * 4 + 1][col] = (unsigned short)(p01 >> 16);
      hbuf[pout][q * 4 + 2][col] = (unsigned short)p23;
      hbuf[pout][q * 4 + 3][col] = (unsigned short)(p23 >> 16);

      cx0 = nx0; cx1 = nx1; cx2 = nx2;
      half_bar();
    };

    for (int s = 0; s + 1 < tc; s += 2) { step(s, 0, 1); step(s + 1, 1, 0); }
    {
      uint2 hv = *(const uint2*)&hbuf[tc & 1][xrow][xc4];
      *(uint2*)(myseq + (size_t)(t0 + tc - 1) * 131072 + hoff) = hv;
    }
    return;
  }

  if (sccum_t0 >= 0) {
    // ========== sccum role: fused score+cumsum, two 512-thr instances ==========
    int rb = bid - sccum_base;
    if (rb < 0 || rb >= 128) return;
    int inst = tid >> 9, t = tid & 511;
    int t0c = sccum_t0;
    int b0c = rb * 8 + inst * 4;
    int w = t >> 6, L = t & 63, l15 = L & 15, q = L >> 4;
    int jc = t & 127, bc = (t >> 7) & 3;
    int b = b0c + bc;
    auto& cmi = lds.cm[inst];

    float c = (t0c == 0) ? 0.0f : cum[(size_t)b * 128 + jc];
    int cap0 = lengths[b] - 4;               // capture window [cap0, cap0+3]

    float hgv[4];
    #pragma unroll
    for (int d = 0; d < 4; d++) {
      int sl = cap0 + d - t0c;
      hgv[d] = (sl >= 0 && sl < 100) ? bf2f(hg[((size_t)(cap0 + d) * 1024 + b) * 128 + jc]) : 0.f;
    }

    // A1/A2 B-fragments for this wave's 16-col strip
    short8 B1[4], B2[4];
    #pragma unroll
    for (int kf = 0; kf < 4; kf++) {
      B1[kf] = *(const short8*)(a12 + (size_t)(w * 16 + l15) * 128 + kf * 32 + q * 8);
      B2[kf] = *(const short8*)(a12 + 16384 + (size_t)(w * 16 + l15) * 128 + kf * 32 + q * 8);
    }
    float v1w = v1[w * 16 + l15];

    for (int seg = 0; seg < 4; seg++) {
      int t0s = t0c + seg * 25;
      __syncthreads();                        // LDS reuse guard (both instances symmetric)
      for (int f8 = t; f8 < 1600; f8 += 512) {
        int sl = f8 >> 6, r8 = f8 & 63, bb = r8 >> 4, j8 = r8 & 15;
        size_t gsrc = ((size_t)(t0s + sl) * 1024 + b0c) * 128 + r8 * 8;
        int dst = sl * 544 + bb * 136 + j8 * 8;
        *(short8*)&cmi.hlL[dst] = *(const short8*)(hl + gsrc);
        *(short8*)&cmi.hgL[dst] = *(const short8*)(hg + gsrc);
      }
      __syncthreads();

      // score partials: 7 MFMA tiles of 16 rows = (4 timesteps x 4 b-rows)
      #pragma unroll
      for (int T = 0; T < 7; T++) {
        int tl = T * 4 + (l15 >> 2); if (tl > 24) tl = 24;
        int bb = l15 & 3;
        int abase = tl * 544 + bb * 136 + q * 8;
        short8 Al[4], Ag[4];
        #pragma unroll
        for (int kf = 0; kf < 4; kf++) {
          Al[kf] = *(const short8*)&cmi.hlL[abase + kf * 32];
          Ag[kf] = *(const short8*)&cmi.hgL[abase + kf * 32];
        }
        float4v acc = (float4v){0.f, 0.f, 0.f, 0.f};
        #pragma unroll
        for (int kf = 0; kf < 4; kf++) acc = __builtin_amdgcn_mfma_f32_16x16x32_bf16(Al[kf], B1[kf], acc, 0,0,0);
        #pragma unroll
        for (int kf = 0; kf < 4; kf++) acc = __builtin_amdgcn_mfma_f32_16x16x32_bf16(Ag[kf], B2[kf], acc, 0,0,0);
        #pragma unroll
        for (int r = 0; r < 4; r++) {
          float sv = v1w * sigm(acc[r]);
          sv += __shfl_xor(sv, 1, 16);
          sv += __shfl_xor(sv, 2, 16);
          sv += __shfl_xor(sv, 4, 16);
          sv += __shfl_xor(sv, 8, 16);
          if (l15 == 0) cmi.part[w * 112 + T * 16 + q * 4 + r] = sv;
        }
      }
      __syncthreads();
      if (t < 100) {
        float s = 0.f;
        #pragma unroll
        for (int w8 = 0; w8 < 8; w8++) s += cmi.part[w8 * 112 + t];
        cmi.scR[t] = s;
      }
      __syncthreads();

      // cumsum + capture over this segment
      for (int sl = 0; sl < 25; sl += 5) {
        float h[5], scv[5];
        #pragma unroll
        for (int k = 0; k < 5; k++) {
          h[k]   = bf2f(cmi.hlL[(sl + k) * 544 + bc * 136 + jc]);
          scv[k] = cmi.scR[(sl + k) * 4 + bc];
        }
        #pragma unroll
        for (int k = 0; k < 5; k++) {
          c += scv[k] * h[k];
          int d = (t0s + sl + k) - cap0;
          if ((unsigned)d < 4u)
            out[((size_t)b * 4 + d) * 128 + jc] = c + hgv[d];
        }
      }
    }
    cum[(size_t)b * 128 + jc] = c;
    return;
  }
}

// ---------------- launch ----------------
extern "C" void kernel_launch(void* const* d_in, const int* in_sizes, int n_in,
                              void* d_out, int out_size, void* d_ws, size_t ws_size,
                              hipStream_t stream)
{
  const float* x     = (const float*)d_in[0];
  const int* lengths = (const int*)d_in[1];
  const float* Wih_g = (const float*)d_in[2];
  const float* Whh_g = (const float*)d_in[3];
  const float* bih_g = (const float*)d_in[4];
  const float* bhh_g = (const float*)d_in[5];
  const float* Wih_l = (const float*)d_in[6];
  const float* Whh_l = (const float*)d_in[7];
  const float* bih_l = (const float*)d_in[8];
  const float* bhh_l = (const float*)d_in[9];
  const float* A1    = (const float*)d_in[10];
  const float* A2    = (const float*)d_in[11];
  const float* v1    = (const float*)d_in[12];
  float* out = (float*)d_out;

  char* wsb = (char*)d_ws;
  size_t o = 0;
  unsigned short* a12 = (unsigned short*)(wsb + o); o += 65536;
  unsigned short* wst = (unsigned short*)(wsb + o); o += 393216;
  float* cum          = (float*)(wsb + o);          o += 524288;
  unsigned short* hl  = (unsigned short*)(wsb + o); o += (size_t)200 * 1024 * 128 * 2;
  unsigned short* hg  = (unsigned short*)(wsb + o); o += (size_t)200 * 1024 * 128 * 2;
  if (o > ws_size) return;

  // L0: weight stash + A1/A2 cast (stream-ordered before L1's stash reads)
  k_build<<<128, 512, 0, stream>>>(Wih_g, Whh_g, Wih_l, Whh_l, A1, A2, wst, a12);
  // L1: scan2 chunk 0
  k_fat<<<64, 1024, 0, stream>>>(x, bih_g, bhh_g, bih_l, bhh_l, wst, a12, v1, lengths,
                                 hl, hg, cum, out, 0, -1, 0);
  // L2: scan2 chunk 1 + sccum chunk 0
  k_fat<<<192, 1024, 0, stream>>>(x, bih_g, bhh_g, bih_l, bhh_l, wst, a12, v1, lengths,
                                  hl, hg, cum, out, 100, 0, 64);
  // L3: sccum chunk 1
  k_fat<<<128, 1024, 0, stream>>>(x, bih_g, bhh_g, bih_l, bhh_l, wst, a12, v1, lengths,
                                  hl, hg, cum, out, -1, 100, 0);
}

// Round 9
// 578.864 us; speedup vs baseline: 2.5385x; 2.5385x over previous
//
#include <hip/hip_runtime.h>
#include <stdint.h>

// NARM fused pipeline v13 for MI355X (gfx950).
//   v12 post-mortem: 1024-thr block spilled to 64 VGPR again (v7 signature);
//   split-phase never tested. v13 reaches the same co-location mechanism with the
//   PROVEN (512,2)/124-VGPR block: shrink per-block batch slice 16->4 valid rows
//   (fragment rows 4-15 = bounded zero-fed garbage, row-confined by MFMA, never
//   stored) -> 512 blocks = 2 blocks/CU, independent s_barriers -> natural
//   anti-phase; one block's MFMA overlaps the other's gate VALU (m114).
//   Two launches only:
//     k_scan : 512 blocks x 512 thr, tc=200, weights direct fp32->bf16 init once
//     k_sccum: 256 blocks x 512 thr, fused score+cumsum (v11's passed role),
//              8 segments of 25 slices, cum carried in registers, A1/A2 inline

typedef __attribute__((ext_vector_type(8))) short short8;
typedef __attribute__((ext_vector_type(4))) float float4v;

// exec+LDS barrier without the full vmcnt drain of __syncthreads()
#define LDS_BARRIER() asm volatile("s_waitcnt lgkmcnt(0)\n\ts_barrier" ::: "memory")

__device__ inline float bf2f(unsigned short u){
  union { unsigned int i; float f; } v; v.i = ((unsigned int)u) << 16; return v.f;
}
__device__ inline unsigned short f2bf(float f){
  union { float f; unsigned int i; } v; v.f = f;
  unsigned int x = v.i;
  return (unsigned short)((x + 0x7fffu + ((x >> 16) & 1u)) >> 16);
}
// HW packed f32->bf16 RNE (identical rounding to f2bf); no builtin on gfx950
__device__ inline unsigned int cvt_pk_bf16(float a, float b){
  unsigned int r;
  asm("v_cvt_pk_bf16_f32 %0, %1, %2" : "=v"(r) : "v"(a), "v"(b));
  return r;
}
__device__ inline float sigm(float x){ return __builtin_amdgcn_rcpf(1.0f + __expf(-x)); }

// ---------------- K1: dual-GRU scan, 4 valid rows/block, 2 blocks/CU ----------------
__global__ __launch_bounds__(512, 2) void k_scan(
    const float* __restrict__ x,
    const float* __restrict__ Wih_g, const float* __restrict__ Whh_g,
    const float* __restrict__ bih_g, const float* __restrict__ bhh_g,
    const float* __restrict__ Wih_l, const float* __restrict__ Whh_l,
    const float* __restrict__ bih_l, const float* __restrict__ bhh_l,
    unsigned short* __restrict__ hl_seq, unsigned short* __restrict__ hg_seq)
{
  __shared__ __align__(16) unsigned short hbuf[2][16][136];
  __shared__ __align__(16) unsigned short xbuf[2][16][136];
  const int tc = 200;
  int tid = threadIdx.x;
  int w = tid >> 6, L = tid & 63, l15 = L & 15, q = L >> 4;
  int gru = blockIdx.x & 1;                 // 0 = g, 1 = l
  int b0 = (blockIdx.x >> 1) * 4;           // 4 valid batch rows per block
  const float* Wih = gru ? Wih_l : Wih_g;
  const float* Whh = gru ? Whh_l : Whh_g;
  const float* bih = gru ? bih_l : bih_g;
  const float* bhh = gru ? bhh_l : bhh_g;
  unsigned short* myseq = gru ? hl_seq : hg_seq;

  int col = w * 16 + l15;                   // this lane's output column

  // register-resident weight B-fragments (fp32 -> bf16 once; weights L2-hot)
  short8 Wi[3][4], Wh[3][4];
  #pragma unroll
  for (int G = 0; G < 3; G++) {
    int row = G * 128 + col;
    #pragma unroll
    for (int kf = 0; kf < 4; kf++) {
      const float4* p0 = (const float4*)(Wih + (size_t)row * 128 + kf * 32 + q * 8);
      const float4* p1 = (const float4*)(Whh + (size_t)row * 128 + kf * 32 + q * 8);
      float4 a0 = p0[0], a1 = p0[1], b0f = p1[0], b1f = p1[1];
      short8 si, sh;
      si[0]=(short)f2bf(a0.x); si[1]=(short)f2bf(a0.y); si[2]=(short)f2bf(a0.z); si[3]=(short)f2bf(a0.w);
      si[4]=(short)f2bf(a1.x); si[5]=(short)f2bf(a1.y); si[6]=(short)f2bf(a1.z); si[7]=(short)f2bf(a1.w);
      sh[0]=(short)f2bf(b0f.x); sh[1]=(short)f2bf(b0f.y); sh[2]=(short)f2bf(b0f.z); sh[3]=(short)f2bf(b0f.w);
      sh[4]=(short)f2bf(b1f.x); sh[5]=(short)f2bf(b1f.y); sh[6]=(short)f2bf(b1f.z); sh[7]=(short)f2bf(b1f.w);
      Wi[G][kf] = si; Wh[G][kf] = sh;
    }
  }
  float br  = bih[col]       + bhh[col];
  float bz  = bih[128 + col] + bhh[128 + col];
  float bin = bih[256 + col];               // bhh_n stays inside r*( ) per PyTorch GRU
  float bnh = bhh[256 + col];

  // init h(-1) = 0 (all 16 fragment rows)
  float hold[4] = {0.f, 0.f, 0.f, 0.f};
  #pragma unroll
  for (int r = 0; r < 4; r++) hbuf[0][q * 4 + r][col] = 0;

  // x staging: only rows 0..3 are real; rows 4..15 zeroed once in BOTH buffers
  // (commits below only touch rows 0..3, so they stay zero -> garbage rows of the
  // recurrence stay bounded: x-contrib = bias only, h rows 4..15 finite forever).
  int xrow = tid >> 5, xc4 = (tid & 31) * 4;
  if (xrow >= 4) {
    *(uint2*)&xbuf[0][xrow][xc4] = make_uint2(0u, 0u);
    *(uint2*)&xbuf[1][xrow][xc4] = make_uint2(0u, 0u);
  }
  size_t hoff = (size_t)(b0 + xrow) * 128 + xc4;   // valid for tid<128 only
  float4 xr = make_float4(0.f, 0.f, 0.f, 0.f);
  if (tid < 128) {
    float4 x0 = *(const float4*)(x + ((size_t)0 * 1024 + b0) * 128 + tid * 4);
    *(uint2*)&xbuf[0][xrow][xc4] = make_uint2(cvt_pk_bf16(x0.x, x0.y), cvt_pk_bf16(x0.z, x0.w));
    xr = *(const float4*)(x + ((size_t)1 * 1024 + b0) * 128 + tid * 4);
  }
  __syncthreads();

  // prologue: x-side chains for step 0 (cx = x(0)@Wih)
  float4v cx0 = (float4v){0.f,0.f,0.f,0.f}, cx1 = cx0, cx2 = cx0;
  {
    short8 Ax[4];
    #pragma unroll
    for (int kf = 0; kf < 4; kf++) Ax[kf] = *(const short8*)&xbuf[0][l15][kf * 32 + q * 8];
    #pragma unroll
    for (int kf = 0; kf < 4; kf++) cx0 = __builtin_amdgcn_mfma_f32_16x16x32_bf16(Ax[kf], Wi[0][kf], cx0, 0,0,0);
    #pragma unroll
    for (int kf = 0; kf < 4; kf++) cx1 = __builtin_amdgcn_mfma_f32_16x16x32_bf16(Ax[kf], Wi[1][kf], cx1, 0,0,0);
    #pragma unroll
    for (int kf = 0; kf < 4; kf++) cx2 = __builtin_amdgcn_mfma_f32_16x16x32_bf16(Ax[kf], Wi[2][kf], cx2, 0,0,0);
  }
  // commit x(1) into xbuf[1]; prefetch x(2)
  if (tid < 128) {
    *(uint2*)&xbuf[1][xrow][xc4] = make_uint2(cvt_pk_bf16(xr.x, xr.y), cvt_pk_bf16(xr.z, xr.w));
    xr = *(const float4*)(x + ((size_t)2 * 1024 + b0) * 128 + tid * 4);
  }
  LDS_BARRIER();

  // step s: pin = s&1 holds h(s-1); pout receives h(s). xbuf[pout] holds x(s+1);
  // xbuf[pin] rows 0..3 are dead -> overwritten with x(s+2). Deferred coalesced
  // store of h(s-1) rows 0..3 only (tid<128).
  auto step = [&](int s, int pin, int pout) {
    short8 Ah[4], Axn[4];
    #pragma unroll
    for (int kf = 0; kf < 4; kf++) Ah[kf]  = *(const short8*)&hbuf[pin][l15][kf * 32 + q * 8];
    #pragma unroll
    for (int kf = 0; kf < 4; kf++) Axn[kf] = *(const short8*)&xbuf[pout][l15][kf * 32 + q * 8];

    if (s > 0 && tid < 128) {
      uint2 hv = *(const uint2*)&hbuf[pin][xrow][xc4];
      *(uint2*)(myseq + (size_t)(s - 1) * 131072 + hoff) = hv;
    }

    // critical-path h-chains first
    float4v rh = (float4v){0.f,0.f,0.f,0.f}, zh = rh, nh = rh;
    #pragma unroll
    for (int kf = 0; kf < 4; kf++) rh = __builtin_amdgcn_mfma_f32_16x16x32_bf16(Ah[kf], Wh[0][kf], rh, 0,0,0);
    #pragma unroll
    for (int kf = 0; kf < 4; kf++) zh = __builtin_amdgcn_mfma_f32_16x16x32_bf16(Ah[kf], Wh[1][kf], zh, 0,0,0);
    #pragma unroll
    for (int kf = 0; kf < 4; kf++) nh = __builtin_amdgcn_mfma_f32_16x16x32_bf16(Ah[kf], Wh[2][kf], nh, 0,0,0);

    // background x-chains for step s+1 (drain during gate phase)
    float4v nx0 = (float4v){0.f,0.f,0.f,0.f}, nx1 = nx0, nx2 = nx0;
    #pragma unroll
    for (int kf = 0; kf < 4; kf++) nx0 = __builtin_amdgcn_mfma_f32_16x16x32_bf16(Axn[kf], Wi[0][kf], nx0, 0,0,0);
    #pragma unroll
    for (int kf = 0; kf < 4; kf++) nx1 = __builtin_amdgcn_mfma_f32_16x16x32_bf16(Axn[kf], Wi[1][kf], nx1, 0,0,0);
    #pragma unroll
    for (int kf = 0; kf < 4; kf++) nx2 = __builtin_amdgcn_mfma_f32_16x16x32_bf16(Axn[kf], Wi[2][kf], nx2, 0,0,0);

    // commit prefetched x(s+2) (rows 0..3); prefetch x(s+3)
    if (tid < 128) {
      *(uint2*)&xbuf[pin][xrow][xc4] = make_uint2(cvt_pk_bf16(xr.x, xr.y), cvt_pk_bf16(xr.z, xr.w));
      int t3 = (s + 3 < tc ? s + 3 : tc - 1);
      xr = *(const float4*)(x + ((size_t)t3 * 1024 + b0) * 128 + tid * 4);
    }

    // x-side gate constants for THIS step (cx computed one step ago)
    float cr[4], cz[4], cn[4];
    #pragma unroll
    for (int r = 0; r < 4; r++) { cr[r] = cx0[r] + br; cz[r] = cx1[r] + bz; cn[r] = cx2[r] + bin; }

    // gates: shared-rcp sigmoid pair + exp-based tanh
    float hnv[4];
    #pragma unroll
    for (int r = 0; r < 4; r++) {
      float er = __expf(-(rh[r] + cr[r]));
      float ez = __expf(-(zh[r] + cz[r]));
      float pr = 1.0f + er, pz = 1.0f + ez;
      float inv = __builtin_amdgcn_rcpf(pr * pz);
      float rr = pz * inv;                  // = 1/(1+er)
      float zz = pr * inv;                  // = 1/(1+ez)
      float y  = cn[r] + rr * (nh[r] + bnh);
      float em = __expf(-2.0f * y);
      float nn = 2.0f * __builtin_amdgcn_rcpf(1.0f + em) - 1.0f;   // tanh(y)
      hnv[r] = nn + zz * (hold[r] - nn);
      hold[r] = hnv[r];
    }
    unsigned int p01 = cvt_pk_bf16(hnv[0], hnv[1]);
    unsigned int p23 = cvt_pk_bf16(hnv[2], hnv[3]);
    hbuf[pout][q * 4 + 0][col] = (unsigned short)p01;
    hbuf[pout][q * 4 + 1][col] = (unsigned short)(p01 >> 16);
    hbuf[pout][q * 4 + 2][col] = (unsigned short)p23;
    hbuf[pout][q * 4 + 3][col] = (unsigned short)(p23 >> 16);

    cx0 = nx0; cx1 = nx1; cx2 = nx2;
    LDS_BARRIER();
  };

  for (int s = 0; s + 1 < tc; s += 2) { step(s, 0, 1); step(s + 1, 1, 0); }
  // epilogue: store h(199) (tc even -> lives in hbuf[0])
  if (tid < 128) {
    uint2 hv = *(const uint2*)&hbuf[tc & 1][xrow][xc4];
    *(uint2*)(myseq + (size_t)(tc - 1) * 131072 + hoff) = hv;
  }
}

// ---------------- K2: fused score + cumsum + capture ----------------
// 256 blocks x 512 thr; block = 4 batch rows x 200 timesteps (8 segments of 25).
__global__ __launch_bounds__(512, 2) void k_sccum(
    const unsigned short* __restrict__ hl, const unsigned short* __restrict__ hg,
    const float* __restrict__ A1, const float* __restrict__ A2,
    const float* __restrict__ v1, const int* __restrict__ lengths,
    float* __restrict__ out)
{
  __shared__ __align__(16) unsigned short hlL[25 * 544];   // [sl][bb*136 + j]
  __shared__ __align__(16) unsigned short hgL[25 * 544];
  __shared__ float part[8 * 112];
  __shared__ float scR[112];
  int tid = threadIdx.x;
  int rb = blockIdx.x;
  int b0c = rb * 4;
  int w = tid >> 6, L = tid & 63, l15 = L & 15, q = L >> 4;
  int jc = tid & 127, bc = (tid >> 7) & 3;
  int b = b0c + bc;

  float c = 0.0f;
  int cap0 = lengths[b] - 4;               // capture window [cap0, cap0+3] in [0,199]

  // preload the 4 h_g capture values (entire sequence is ready)
  float hgv[4];
  #pragma unroll
  for (int d = 0; d < 4; d++)
    hgv[d] = bf2f(hg[((size_t)(cap0 + d) * 1024 + b) * 128 + jc]);

  // A1/A2 B-fragments for this wave's 16-col strip: fp32 -> bf16 inline
  short8 B1[4], B2[4];
  #pragma unroll
  for (int kf = 0; kf < 4; kf++) {
    const float4* p1 = (const float4*)(A1 + (size_t)(w * 16 + l15) * 128 + kf * 32 + q * 8);
    const float4* p2 = (const float4*)(A2 + (size_t)(w * 16 + l15) * 128 + kf * 32 + q * 8);
    float4 a0 = p1[0], a1 = p1[1], c0 = p2[0], c1 = p2[1];
    short8 s1, s2;
    s1[0]=(short)f2bf(a0.x); s1[1]=(short)f2bf(a0.y); s1[2]=(short)f2bf(a0.z); s1[3]=(short)f2bf(a0.w);
    s1[4]=(short)f2bf(a1.x); s1[5]=(short)f2bf(a1.y); s1[6]=(short)f2bf(a1.z); s1[7]=(short)f2bf(a1.w);
    s2[0]=(short)f2bf(c0.x); s2[1]=(short)f2bf(c0.y); s2[2]=(short)f2bf(c0.z); s2[3]=(short)f2bf(c0.w);
    s2[4]=(short)f2bf(c1.x); s2[5]=(short)f2bf(c1.y); s2[6]=(short)f2bf(c1.z); s2[7]=(short)f2bf(c1.w);
    B1[kf] = s1; B2[kf] = s2;
  }
  float v1w = v1[w * 16 + l15];

  for (int seg = 0; seg < 8; seg++) {
    int t0s = seg * 25;
    __syncthreads();                        // LDS reuse guard
    // stage hl/hg rows [t0s, t0s+25) x 4 b-rows (coalesced short8, padded dst)
    for (int f8 = tid; f8 < 1600; f8 += 512) {
      int sl = f8 >> 6, r8 = f8 & 63, bb = r8 >> 4, j8 = r8 & 15;
      size_t gsrc = ((size_t)(t0s + sl) * 1024 + b0c) * 128 + r8 * 8;
      int dst = sl * 544 + bb * 136 + j8 * 8;
      *(short8*)&hlL[dst] = *(const short8*)(hl + gsrc);
      *(short8*)&hgL[dst] = *(const short8*)(hg + gsrc);
    }
    __syncthreads();

    // score partials: 7 MFMA tiles of 16 rows = (4 timesteps x 4 b-rows)
    #pragma unroll
    for (int T = 0; T < 7; T++) {
      int tl = T * 4 + (l15 >> 2); if (tl > 24) tl = 24;
      int bb = l15 & 3;
      int abase = tl * 544 + bb * 136 + q * 8;
      short8 Al[4], Ag[4];
      #pragma unroll
      for (int kf = 0; kf < 4; kf++) {
        Al[kf] = *(const short8*)&hlL[abase + kf * 32];
        Ag[kf] = *(const short8*)&hgL[abase + kf * 32];
      }
      float4v acc = (float4v){0.f, 0.f, 0.f, 0.f};
      #pragma unroll
      for (int kf = 0; kf < 4; kf++) acc = __builtin_amdgcn_mfma_f32_16x16x32_bf16(Al[kf], B1[kf], acc, 0,0,0);
      #pragma unroll
      for (int kf = 0; kf < 4; kf++) acc = __builtin_amdgcn_mfma_f32_16x16x32_bf16(Ag[kf], B2[kf], acc, 0,0,0);
      #pragma unroll
      for (int r = 0; r < 4; r++) {
        float sv = v1w * sigm(acc[r]);
        sv += __shfl_xor(sv, 1, 16);
        sv += __shfl_xor(sv, 2, 16);
        sv += __shfl_xor(sv, 4, 16);
        sv += __shfl_xor(sv, 8, 16);
        if (l15 == 0) part[w * 112 + T * 16 + q * 4 + r] = sv;
      }
    }
    __syncthreads();
    // finalize: row = sl*4 + b (sl in [0,25), b in [0,4)); rows 100..111 garbage
    if (tid < 100) {
      float s = 0.f;
      #pragma unroll
      for (int w8 = 0; w8 < 8; w8++) s += part[w8 * 112 + tid];
      scR[tid] = s;
    }
    __syncthreads();

    // cumsum + capture over this segment
    for (int sl = 0; sl < 25; sl += 5) {
      float h[5], scv[5];
      #pragma unroll
      for (int k = 0; k < 5; k++) {
        h[k]   = bf2f(hlL[(sl + k) * 544 + bc * 136 + jc]);
        scv[k] = scR[(sl + k) * 4 + bc];
      }
      #pragma unroll
      for (int k = 0; k < 5; k++) {
        c += scv[k] * h[k];
        int d = (t0s + sl + k) - cap0;
        if ((unsigned)d < 4u)
          out[((size_t)b * 4 + d) * 128 + jc] = c + hgv[d];
      }
    }
  }
}

// ---------------- launch ----------------
extern "C" void kernel_launch(void* const* d_in, const int* in_sizes, int n_in,
                              void* d_out, int out_size, void* d_ws, size_t ws_size,
                              hipStream_t stream)
{
  const float* x     = (const float*)d_in[0];
  const int* lengths = (const int*)d_in[1];
  const float* Wih_g = (const float*)d_in[2];
  const float* Whh_g = (const float*)d_in[3];
  const float* bih_g = (const float*)d_in[4];
  const float* bhh_g = (const float*)d_in[5];
  const float* Wih_l = (const float*)d_in[6];
  const float* Whh_l = (const float*)d_in[7];
  const float* bih_l = (const float*)d_in[8];
  const float* bhh_l = (const float*)d_in[9];
  const float* A1    = (const float*)d_in[10];
  const float* A2    = (const float*)d_in[11];
  const float* v1    = (const float*)d_in[12];
  float* out = (float*)d_out;

  char* wsb = (char*)d_ws;
  size_t o = 0;
  unsigned short* hl = (unsigned short*)(wsb + o); o += (size_t)200 * 1024 * 128 * 2;
  unsigned short* hg = (unsigned short*)(wsb + o); o += (size_t)200 * 1024 * 128 * 2;
  if (o > ws_size) return;

  k_scan<<<512, 512, 0, stream>>>(x, Wih_g, Whh_g, bih_g, bhh_g,
                                  Wih_l, Whh_l, bih_l, bhh_l, hl, hg);
  k_sccum<<<256, 512, 0, stream>>>(hl, hg, A1, A2, v1, lengths, out);
}

// Round 10
// 503.766 us; speedup vs baseline: 2.9169x; 1.1491x over previous
//
#include <hip/hip_runtime.h>
#include <stdint.h>

// NARM fused pipeline v14 for MI355X (gfx950).
//   v13 post-mortem: 2 blocks/CU co-location achieved (Occ 23.5%, both pipes up)
//   but step = MFMA + VALU + latency (pipes SUM, not max, even across blocks)
//   -> scan's 233us (v6 config) is the issue-bandwidth floor for the atomic
//   16x128 recurrence tile on 128 CUs. Stop attacking the scan.
//   The tail (fused score+cumsum) measured ~130-150us for ~13 GFLOP + an
//   L3-resident 104MB read: the per-segment stage->sync(vmcnt drain)->compute
//   structure exposes HBM latency 8x with no overlap.
//   v14 = 2 launches:
//     k_scan : v6's proven fused dual-GRU scan, verbatim, tc=200, zero-init
//     k_sccum: barrier-free fused score+cumsum: MFMA A-fragments read DIRECTLY
//              from global (8 waves share 8KB/tile -> L1 hits; data L2/L3-hot
//              from scan); no barriers in the 50-tile loop -> loads pipeline
//              under MFMA; only 2 syncthreads total (cross-wave reduce).

typedef __attribute__((ext_vector_type(8))) short short8;
typedef __attribute__((ext_vector_type(4))) float float4v;

// exec+LDS barrier without the full vmcnt drain of __syncthreads()
#define LDS_BARRIER() asm volatile("s_waitcnt lgkmcnt(0)\n\ts_barrier" ::: "memory")

__device__ inline float bf2f(unsigned short u){
  union { unsigned int i; float f; } v; v.i = ((unsigned int)u) << 16; return v.f;
}
__device__ inline unsigned short f2bf(float f){
  union { float f; unsigned int i; } v; v.f = f;
  unsigned int x = v.i;
  return (unsigned short)((x + 0x7fffu + ((x >> 16) & 1u)) >> 16);
}
// HW packed f32->bf16 RNE (identical rounding to f2bf); no builtin on gfx950
__device__ inline unsigned int cvt_pk_bf16(float a, float b){
  unsigned int r;
  asm("v_cvt_pk_bf16_f32 %0, %1, %2" : "=v"(r) : "v"(a), "v"(b));
  return r;
}
__device__ inline float sigm(float x){ return __builtin_amdgcn_rcpf(1.0f + __expf(-x)); }

// ---------------- K1: fused dual-GRU scan (v6 verbatim, tc=200, zero-init) ----------------
// grid 128 = (64 batch-groups x 2 GRUs), block 512 (8 waves, 16 cols each).
__global__ __launch_bounds__(512, 2) void k_scan(
    const float* __restrict__ x,
    const float* __restrict__ Wih_g, const float* __restrict__ Whh_g,
    const float* __restrict__ bih_g, const float* __restrict__ bhh_g,
    const float* __restrict__ Wih_l, const float* __restrict__ Whh_l,
    const float* __restrict__ bih_l, const float* __restrict__ bhh_l,
    unsigned short* __restrict__ hl_seq, unsigned short* __restrict__ hg_seq)
{
  __shared__ __align__(16) unsigned short hbuf[2][16][136];
  __shared__ __align__(16) unsigned short xbuf[2][16][136];
  const int tc = 200;
  int tid = threadIdx.x;
  int w = tid >> 6, L = tid & 63, l15 = L & 15, q = L >> 4;
  int gru = blockIdx.x & 1;                 // 0 = g, 1 = l
  int b0 = (blockIdx.x >> 1) * 16;
  const float* Wih = gru ? Wih_l : Wih_g;
  const float* Whh = gru ? Whh_l : Whh_g;
  const float* bih = gru ? bih_l : bih_g;
  const float* bhh = gru ? bhh_l : bhh_g;
  unsigned short* myseq = gru ? hl_seq : hg_seq;

  int col = w * 16 + l15;                   // this lane's output column

  // register-resident weight B-fragments (fp32 -> bf16 once per launch)
  short8 Wi[3][4], Wh[3][4];
  #pragma unroll
  for (int G = 0; G < 3; G++) {
    int row = G * 128 + col;
    #pragma unroll
    for (int kf = 0; kf < 4; kf++) {
      const float4* p0 = (const float4*)(Wih + (size_t)row * 128 + kf * 32 + q * 8);
      const float4* p1 = (const float4*)(Whh + (size_t)row * 128 + kf * 32 + q * 8);
      float4 a0 = p0[0], a1 = p0[1], b0f = p1[0], b1f = p1[1];
      short8 si, sh;
      si[0]=(short)f2bf(a0.x); si[1]=(short)f2bf(a0.y); si[2]=(short)f2bf(a0.z); si[3]=(short)f2bf(a0.w);
      si[4]=(short)f2bf(a1.x); si[5]=(short)f2bf(a1.y); si[6]=(short)f2bf(a1.z); si[7]=(short)f2bf(a1.w);
      sh[0]=(short)f2bf(b0f.x); sh[1]=(short)f2bf(b0f.y); sh[2]=(short)f2bf(b0f.z); sh[3]=(short)f2bf(b0f.w);
      sh[4]=(short)f2bf(b1f.x); sh[5]=(short)f2bf(b1f.y); sh[6]=(short)f2bf(b1f.z); sh[7]=(short)f2bf(b1f.w);
      Wi[G][kf] = si; Wh[G][kf] = sh;
    }
  }
  float br  = bih[col]       + bhh[col];
  float bz  = bih[128 + col] + bhh[128 + col];
  float bin = bih[256 + col];               // bhh_n stays inside r*( ) per PyTorch GRU
  float bnh = bhh[256 + col];

  // h(-1) = 0 (registers + LDS; no prep kernel needed)
  float hold[4] = {0.f, 0.f, 0.f, 0.f};
  #pragma unroll
  for (int r = 0; r < 4; r++) hbuf[0][q * 4 + r][col] = 0;

  // stage x(0) into xbuf[0]; prefetch x(1) into regs
  int xrow = tid >> 5, xc4 = (tid & 31) * 4;
  {
    float4 x0 = ((const float4*)(x + (size_t)b0 * 128))[tid];
    *(uint2*)&xbuf[0][xrow][xc4] = make_uint2(cvt_pk_bf16(x0.x, x0.y), cvt_pk_bf16(x0.z, x0.w));
  }
  float4 xr = ((const float4*)(x + ((size_t)1 * 1024 + b0) * 128))[tid];
  __syncthreads();

  // prologue: x-side chains for step 0 (cx = x(0)@Wih)
  float4v cx0 = (float4v){0.f,0.f,0.f,0.f}, cx1 = cx0, cx2 = cx0;
  {
    short8 Ax[4];
    #pragma unroll
    for (int kf = 0; kf < 4; kf++) Ax[kf] = *(const short8*)&xbuf[0][l15][kf * 32 + q * 8];
    #pragma unroll
    for (int kf = 0; kf < 4; kf++) cx0 = __builtin_amdgcn_mfma_f32_16x16x32_bf16(Ax[kf], Wi[0][kf], cx0, 0,0,0);
    #pragma unroll
    for (int kf = 0; kf < 4; kf++) cx1 = __builtin_amdgcn_mfma_f32_16x16x32_bf16(Ax[kf], Wi[1][kf], cx1, 0,0,0);
    #pragma unroll
    for (int kf = 0; kf < 4; kf++) cx2 = __builtin_amdgcn_mfma_f32_16x16x32_bf16(Ax[kf], Wi[2][kf], cx2, 0,0,0);
  }
  // commit x(1) into xbuf[1]; prefetch x(2)
  *(uint2*)&xbuf[1][xrow][xc4] = make_uint2(cvt_pk_bf16(xr.x, xr.y), cvt_pk_bf16(xr.z, xr.w));
  xr = ((const float4*)(x + ((size_t)2 * 1024 + b0) * 128))[tid];
  LDS_BARRIER();

  // hoisted output pointer: stores at opq[r*128] with immediate offsets
  unsigned short* opq = myseq + ((size_t)(b0 + q * 4)) * 128 + col;

  auto step = [&](int s, int pin, int pout) {
    short8 Ah[4], Axn[4];
    #pragma unroll
    for (int kf = 0; kf < 4; kf++) Ah[kf]  = *(const short8*)&hbuf[pin][l15][kf * 32 + q * 8];
    #pragma unroll
    for (int kf = 0; kf < 4; kf++) Axn[kf] = *(const short8*)&xbuf[pout][l15][kf * 32 + q * 8];

    // critical-path h-chains first
    float4v rh = (float4v){0.f,0.f,0.f,0.f}, zh = rh, nh = rh;
    #pragma unroll
    for (int kf = 0; kf < 4; kf++) rh = __builtin_amdgcn_mfma_f32_16x16x32_bf16(Ah[kf], Wh[0][kf], rh, 0,0,0);
    #pragma unroll
    for (int kf = 0; kf < 4; kf++) zh = __builtin_amdgcn_mfma_f32_16x16x32_bf16(Ah[kf], Wh[1][kf], zh, 0,0,0);
    #pragma unroll
    for (int kf = 0; kf < 4; kf++) nh = __builtin_amdgcn_mfma_f32_16x16x32_bf16(Ah[kf], Wh[2][kf], nh, 0,0,0);

    // background x-chains for step s+1 (drain during gate phase)
    float4v nx0 = (float4v){0.f,0.f,0.f,0.f}, nx1 = nx0, nx2 = nx0;
    #pragma unroll
    for (int kf = 0; kf < 4; kf++) nx0 = __builtin_amdgcn_mfma_f32_16x16x32_bf16(Axn[kf], Wi[0][kf], nx0, 0,0,0);
    #pragma unroll
    for (int kf = 0; kf < 4; kf++) nx1 = __builtin_amdgcn_mfma_f32_16x16x32_bf16(Axn[kf], Wi[1][kf], nx1, 0,0,0);
    #pragma unroll
    for (int kf = 0; kf < 4; kf++) nx2 = __builtin_amdgcn_mfma_f32_16x16x32_bf16(Axn[kf], Wi[2][kf], nx2, 0,0,0);

    // commit prefetched x(s+2) into the dead buffer; issue prefetch of x(s+3)
    *(uint2*)&xbuf[pin][xrow][xc4] = make_uint2(cvt_pk_bf16(xr.x, xr.y), cvt_pk_bf16(xr.z, xr.w));
    {
      int t3 = (s + 3 < tc ? s + 3 : tc - 1);
      xr = ((const float4*)(x + ((size_t)t3 * 1024 + b0) * 128))[tid];
    }

    // x-side gate constants for THIS step (cx computed one step ago)
    float cr[4], cz[4], cn[4];
    #pragma unroll
    for (int r = 0; r < 4; r++) { cr[r] = cx0[r] + br; cz[r] = cx1[r] + bz; cn[r] = cx2[r] + bin; }

    // gates: shared-rcp sigmoid pair + exp-based tanh
    float hnv[4];
    #pragma unroll
    for (int r = 0; r < 4; r++) {
      float er = __expf(-(rh[r] + cr[r]));
      float ez = __expf(-(zh[r] + cz[r]));
      float pr = 1.0f + er, pz = 1.0f + ez;
      float inv = __builtin_amdgcn_rcpf(pr * pz);
      float rr = pz * inv;                  // = 1/(1+er)
      float zz = pr * inv;                  // = 1/(1+ez)
      float y  = cn[r] + rr * (nh[r] + bnh);
      float em = __expf(-2.0f * y);
      float nn = 2.0f * __builtin_amdgcn_rcpf(1.0f + em) - 1.0f;   // tanh(y)
      hnv[r] = nn + zz * (hold[r] - nn);
      hold[r] = hnv[r];
    }
    unsigned int p01 = cvt_pk_bf16(hnv[0], hnv[1]);
    unsigned int p23 = cvt_pk_bf16(hnv[2], hnv[3]);
    unsigned short h0 = (unsigned short)p01, h1 = (unsigned short)(p01 >> 16);
    unsigned short h2 = (unsigned short)p23, h3 = (unsigned short)(p23 >> 16);
    hbuf[pout][q * 4 + 0][col] = h0;
    hbuf[pout][q * 4 + 1][col] = h1;
    hbuf[pout][q * 4 + 2][col] = h2;
    hbuf[pout][q * 4 + 3][col] = h3;
    opq[0]   = h0;
    opq[128] = h1;
    opq[256] = h2;
    opq[384] = h3;

    cx0 = nx0; cx1 = nx1; cx2 = nx2;
    opq += 131072;                          // advance one timestep (1024*128)
    LDS_BARRIER();
  };

  for (int s = 0; s + 1 < tc; s += 2) { step(s, 0, 1); step(s + 1, 1, 0); }
}

// ---------------- K2: barrier-free fused score + cumsum + capture ----------------
// 256 blocks x 512 thr; block = 4 batch rows x 200 timesteps.
// Score phase: 50 MFMA tiles (each 16 rows = 4 timesteps x 4 batch rows), A-frags
// loaded DIRECTLY from global (L1-shared across the 8 waves, no LDS staging, no
// barriers in the loop). Cross-wave reduce via part[]; then register cumsum.
__global__ __launch_bounds__(512, 2) void k_sccum(
    const unsigned short* __restrict__ hl, const unsigned short* __restrict__ hg,
    const float* __restrict__ A1, const float* __restrict__ A2,
    const float* __restrict__ v1, const int* __restrict__ lengths,
    float* __restrict__ out)
{
  __shared__ float part[8][800];    // [wave][t*4 + b_local]
  __shared__ float scR[800];
  int tid = threadIdx.x;
  int b0c = blockIdx.x * 4;
  int w = tid >> 6, L = tid & 63, l15 = L & 15, q = L >> 4;

  // A1/A2 B-fragments for this wave's 16-col strip (fp32 -> bf16 inline; L2-hot)
  short8 B1[4], B2[4];
  #pragma unroll
  for (int kf = 0; kf < 4; kf++) {
    const float4* p1 = (const float4*)(A1 + (size_t)(w * 16 + l15) * 128 + kf * 32 + q * 8);
    const float4* p2 = (const float4*)(A2 + (size_t)(w * 16 + l15) * 128 + kf * 32 + q * 8);
    float4 a0 = p1[0], a1 = p1[1], c0 = p2[0], c1 = p2[1];
    short8 s1, s2;
    s1[0]=(short)f2bf(a0.x); s1[1]=(short)f2bf(a0.y); s1[2]=(short)f2bf(a0.z); s1[3]=(short)f2bf(a0.w);
    s1[4]=(short)f2bf(a1.x); s1[5]=(short)f2bf(a1.y); s1[6]=(short)f2bf(a1.z); s1[7]=(short)f2bf(a1.w);
    s2[0]=(short)f2bf(c0.x); s2[1]=(short)f2bf(c0.y); s2[2]=(short)f2bf(c0.z); s2[3]=(short)f2bf(c0.w);
    s2[4]=(short)f2bf(c1.x); s2[5]=(short)f2bf(c1.y); s2[6]=(short)f2bf(c1.z); s2[7]=(short)f2bf(c1.w);
    B1[kf] = s1; B2[kf] = s2;
  }
  float v1w = v1[w * 16 + l15];

  // A-row source for this lane: tile row l15 = (t_off = l15>>2, b = b0c + (l15&3))
  const unsigned short* baseL = hl + ((size_t)(l15 >> 2) * 1024 + b0c + (l15 & 3)) * 128 + q * 8;
  const unsigned short* baseG = hg + ((size_t)(l15 >> 2) * 1024 + b0c + (l15 & 3)) * 128 + q * 8;

  for (int T = 0; T < 50; T++) {
    size_t toff = (size_t)T * 524288;       // 4 timesteps * 1024 * 128
    short8 Al[4], Ag[4];
    #pragma unroll
    for (int kf = 0; kf < 4; kf++) {
      Al[kf] = *(const short8*)(baseL + toff + kf * 32);
      Ag[kf] = *(const short8*)(baseG + toff + kf * 32);
    }
    float4v acc = (float4v){0.f, 0.f, 0.f, 0.f};
    #pragma unroll
    for (int kf = 0; kf < 4; kf++) acc = __builtin_amdgcn_mfma_f32_16x16x32_bf16(Al[kf], B1[kf], acc, 0,0,0);
    #pragma unroll
    for (int kf = 0; kf < 4; kf++) acc = __builtin_amdgcn_mfma_f32_16x16x32_bf16(Ag[kf], B2[kf], acc, 0,0,0);
    // C row q*4+r -> (t = T*4+q, b_local = r); col = w*16+l15
    #pragma unroll
    for (int r = 0; r < 4; r++) {
      float sv = v1w * sigm(acc[r]);
      sv += __shfl_xor(sv, 1, 16);
      sv += __shfl_xor(sv, 2, 16);
      sv += __shfl_xor(sv, 4, 16);
      sv += __shfl_xor(sv, 8, 16);
      if (l15 == 0) part[w][(T * 4 + q) * 4 + r] = sv;
    }
  }
  __syncthreads();
  for (int i = tid; i < 800; i += 512) {
    float s = part[0][i] + part[1][i] + part[2][i] + part[3][i]
            + part[4][i] + part[5][i] + part[6][i] + part[7][i];
    scR[i] = s;
  }
  __syncthreads();

  // cumsum + capture: thread = (b_local, j); hl re-reads are L2/L3-hot
  int jc = tid & 127, bc = tid >> 7;        // bc in [0,4)
  int b = b0c + bc;
  float c = 0.0f;
  int cap0 = lengths[b] - 4;                // capture window [cap0, cap0+3] in [0,196]
  float hgv[4];
  #pragma unroll
  for (int d = 0; d < 4; d++)
    hgv[d] = bf2f(hg[((size_t)(cap0 + d) * 1024 + b) * 128 + jc]);

  const unsigned short* hp = hl + (size_t)b * 128 + jc;
  for (int t = 0; t < 200; t += 5) {
    float h[5], s5[5];
    #pragma unroll
    for (int k = 0; k < 5; k++) {
      h[k]  = bf2f(hp[(size_t)(t + k) * 131072]);
      s5[k] = scR[(t + k) * 4 + bc];
    }
    #pragma unroll
    for (int k = 0; k < 5; k++) {
      c += s5[k] * h[k];
      int d = (t + k) - cap0;
      if ((unsigned)d < 4u)
        out[((size_t)b * 4 + d) * 128 + jc] = c + hgv[d];
    }
  }
}

// ---------------- launch ----------------
extern "C" void kernel_launch(void* const* d_in, const int* in_sizes, int n_in,
                              void* d_out, int out_size, void* d_ws, size_t ws_size,
                              hipStream_t stream)
{
  const float* x     = (const float*)d_in[0];
  const int* lengths = (const int*)d_in[1];
  const float* Wih_g = (const float*)d_in[2];
  const float* Whh_g = (const float*)d_in[3];
  const float* bih_g = (const float*)d_in[4];
  const float* bhh_g = (const float*)d_in[5];
  const float* Wih_l = (const float*)d_in[6];
  const float* Whh_l = (const float*)d_in[7];
  const float* bih_l = (const float*)d_in[8];
  const float* bhh_l = (const float*)d_in[9];
  const float* A1    = (const float*)d_in[10];
  const float* A2    = (const float*)d_in[11];
  const float* v1    = (const float*)d_in[12];
  float* out = (float*)d_out;

  char* wsb = (char*)d_ws;
  size_t o = 0;
  unsigned short* hl = (unsigned short*)(wsb + o); o += (size_t)200 * 1024 * 128 * 2;
  unsigned short* hg = (unsigned short*)(wsb + o); o += (size_t)200 * 1024 * 128 * 2;
  if (o > ws_size) return;

  k_scan<<<128, 512, 0, stream>>>(x, Wih_g, Whh_g, bih_g, bhh_g,
                                  Wih_l, Whh_l, bih_l, bhh_l, hl, hg);
  k_sccum<<<256, 512, 0, stream>>>(hl, hg, A1, A2, v1, lengths, out);
}

// Round 11
// 480.529 us; speedup vs baseline: 3.0579x; 1.0484x over previous
//
#include <hip/hip_runtime.h>
#include <stdint.h>

// NARM fused pipeline v15 for MI355X (gfx950).
//   v14 post-mortem: k_scan exactly on model (232us). Tail localized: v11/v14
//   sccum both ran ~1.2us/step because of barrier-locked 8-wave phases (same
//   disease as the scan). Tail floor is ~40-60us (13.4 GFLOP + 156MB L3-hot).
//   v15 tail = barrier-free wave-autonomous kernels:
//     k_build : pre-cast A1|A2 -> bf16 a12 (3us)
//     k_scan  : v6/v14 proven scan, verbatim (232us)
//     k_score2: 12800 independent waves; wave = one 16-row (t,b)-tile; A-frags
//               in regs once, loop 8 col-strips (B from a12, L1-hot), per-lane
//               psum, ONE shfl-reduce per tile, no LDS, no syncthreads.
//     k_cum   : v4's proven LDS-staged cumsum+capture (512 blocks, 2/CU),
//               c=0 init, no cum buffer.

typedef __attribute__((ext_vector_type(8))) short short8;
typedef __attribute__((ext_vector_type(4))) float float4v;

// exec+LDS barrier without the full vmcnt drain of __syncthreads()
#define LDS_BARRIER() asm volatile("s_waitcnt lgkmcnt(0)\n\ts_barrier" ::: "memory")

__device__ inline float bf2f(unsigned short u){
  union { unsigned int i; float f; } v; v.i = ((unsigned int)u) << 16; return v.f;
}
__device__ inline unsigned short f2bf(float f){
  union { float f; unsigned int i; } v; v.f = f;
  unsigned int x = v.i;
  return (unsigned short)((x + 0x7fffu + ((x >> 16) & 1u)) >> 16);
}
// HW packed f32->bf16 RNE (identical rounding to f2bf); no builtin on gfx950
__device__ inline unsigned int cvt_pk_bf16(float a, float b){
  unsigned int r;
  asm("v_cvt_pk_bf16_f32 %0, %1, %2" : "=v"(r) : "v"(a), "v"(b));
  return r;
}
__device__ inline float sigm(float x){ return __builtin_amdgcn_rcpf(1.0f + __expf(-x)); }

// ---------------- K0: a12 = bf16(A1 | A2) ----------------
__global__ __launch_bounds__(512) void k_build(const float* __restrict__ A1,
                                               const float* __restrict__ A2,
                                               unsigned short* __restrict__ a12)
{
  int i = blockIdx.x * 512 + threadIdx.x;     // grid 64 -> 32768
  a12[i] = f2bf((i < 16384) ? A1[i] : A2[i - 16384]);
}

// ---------------- K1: fused dual-GRU scan (proven, tc=200, zero-init) ----------------
// grid 128 = (64 batch-groups x 2 GRUs), block 512 (8 waves, 16 cols each).
__global__ __launch_bounds__(512, 2) void k_scan(
    const float* __restrict__ x,
    const float* __restrict__ Wih_g, const float* __restrict__ Whh_g,
    const float* __restrict__ bih_g, const float* __restrict__ bhh_g,
    const float* __restrict__ Wih_l, const float* __restrict__ Whh_l,
    const float* __restrict__ bih_l, const float* __restrict__ bhh_l,
    unsigned short* __restrict__ hl_seq, unsigned short* __restrict__ hg_seq)
{
  __shared__ __align__(16) unsigned short hbuf[2][16][136];
  __shared__ __align__(16) unsigned short xbuf[2][16][136];
  const int tc = 200;
  int tid = threadIdx.x;
  int w = tid >> 6, L = tid & 63, l15 = L & 15, q = L >> 4;
  int gru = blockIdx.x & 1;                 // 0 = g, 1 = l
  int b0 = (blockIdx.x >> 1) * 16;
  const float* Wih = gru ? Wih_l : Wih_g;
  const float* Whh = gru ? Whh_l : Whh_g;
  const float* bih = gru ? bih_l : bih_g;
  const float* bhh = gru ? bhh_l : bhh_g;
  unsigned short* myseq = gru ? hl_seq : hg_seq;

  int col = w * 16 + l15;                   // this lane's output column

  // register-resident weight B-fragments (fp32 -> bf16 once per launch)
  short8 Wi[3][4], Wh[3][4];
  #pragma unroll
  for (int G = 0; G < 3; G++) {
    int row = G * 128 + col;
    #pragma unroll
    for (int kf = 0; kf < 4; kf++) {
      const float4* p0 = (const float4*)(Wih + (size_t)row * 128 + kf * 32 + q * 8);
      const float4* p1 = (const float4*)(Whh + (size_t)row * 128 + kf * 32 + q * 8);
      float4 a0 = p0[0], a1 = p0[1], b0f = p1[0], b1f = p1[1];
      short8 si, sh;
      si[0]=(short)f2bf(a0.x); si[1]=(short)f2bf(a0.y); si[2]=(short)f2bf(a0.z); si[3]=(short)f2bf(a0.w);
      si[4]=(short)f2bf(a1.x); si[5]=(short)f2bf(a1.y); si[6]=(short)f2bf(a1.z); si[7]=(short)f2bf(a1.w);
      sh[0]=(short)f2bf(b0f.x); sh[1]=(short)f2bf(b0f.y); sh[2]=(short)f2bf(b0f.z); sh[3]=(short)f2bf(b0f.w);
      sh[4]=(short)f2bf(b1f.x); sh[5]=(short)f2bf(b1f.y); sh[6]=(short)f2bf(b1f.z); sh[7]=(short)f2bf(b1f.w);
      Wi[G][kf] = si; Wh[G][kf] = sh;
    }
  }
  float br  = bih[col]       + bhh[col];
  float bz  = bih[128 + col] + bhh[128 + col];
  float bin = bih[256 + col];               // bhh_n stays inside r*( ) per PyTorch GRU
  float bnh = bhh[256 + col];

  // h(-1) = 0 (registers + LDS; no prep kernel needed)
  float hold[4] = {0.f, 0.f, 0.f, 0.f};
  #pragma unroll
  for (int r = 0; r < 4; r++) hbuf[0][q * 4 + r][col] = 0;

  // stage x(0) into xbuf[0]; prefetch x(1) into regs
  int xrow = tid >> 5, xc4 = (tid & 31) * 4;
  {
    float4 x0 = ((const float4*)(x + (size_t)b0 * 128))[tid];
    *(uint2*)&xbuf[0][xrow][xc4] = make_uint2(cvt_pk_bf16(x0.x, x0.y), cvt_pk_bf16(x0.z, x0.w));
  }
  float4 xr = ((const float4*)(x + ((size_t)1 * 1024 + b0) * 128))[tid];
  __syncthreads();

  // prologue: x-side chains for step 0 (cx = x(0)@Wih)
  float4v cx0 = (float4v){0.f,0.f,0.f,0.f}, cx1 = cx0, cx2 = cx0;
  {
    short8 Ax[4];
    #pragma unroll
    for (int kf = 0; kf < 4; kf++) Ax[kf] = *(const short8*)&xbuf[0][l15][kf * 32 + q * 8];
    #pragma unroll
    for (int kf = 0; kf < 4; kf++) cx0 = __builtin_amdgcn_mfma_f32_16x16x32_bf16(Ax[kf], Wi[0][kf], cx0, 0,0,0);
    #pragma unroll
    for (int kf = 0; kf < 4; kf++) cx1 = __builtin_amdgcn_mfma_f32_16x16x32_bf16(Ax[kf], Wi[1][kf], cx1, 0,0,0);
    #pragma unroll
    for (int kf = 0; kf < 4; kf++) cx2 = __builtin_amdgcn_mfma_f32_16x16x32_bf16(Ax[kf], Wi[2][kf], cx2, 0,0,0);
  }
  // commit x(1) into xbuf[1]; prefetch x(2)
  *(uint2*)&xbuf[1][xrow][xc4] = make_uint2(cvt_pk_bf16(xr.x, xr.y), cvt_pk_bf16(xr.z, xr.w));
  xr = ((const float4*)(x + ((size_t)2 * 1024 + b0) * 128))[tid];
  LDS_BARRIER();

  // hoisted output pointer: stores at opq[r*128] with immediate offsets
  unsigned short* opq = myseq + ((size_t)(b0 + q * 4)) * 128 + col;

  auto step = [&](int s, int pin, int pout) {
    short8 Ah[4], Axn[4];
    #pragma unroll
    for (int kf = 0; kf < 4; kf++) Ah[kf]  = *(const short8*)&hbuf[pin][l15][kf * 32 + q * 8];
    #pragma unroll
    for (int kf = 0; kf < 4; kf++) Axn[kf] = *(const short8*)&xbuf[pout][l15][kf * 32 + q * 8];

    // critical-path h-chains first
    float4v rh = (float4v){0.f,0.f,0.f,0.f}, zh = rh, nh = rh;
    #pragma unroll
    for (int kf = 0; kf < 4; kf++) rh = __builtin_amdgcn_mfma_f32_16x16x32_bf16(Ah[kf], Wh[0][kf], rh, 0,0,0);
    #pragma unroll
    for (int kf = 0; kf < 4; kf++) zh = __builtin_amdgcn_mfma_f32_16x16x32_bf16(Ah[kf], Wh[1][kf], zh, 0,0,0);
    #pragma unroll
    for (int kf = 0; kf < 4; kf++) nh = __builtin_amdgcn_mfma_f32_16x16x32_bf16(Ah[kf], Wh[2][kf], nh, 0,0,0);

    // background x-chains for step s+1 (drain during gate phase)
    float4v nx0 = (float4v){0.f,0.f,0.f,0.f}, nx1 = nx0, nx2 = nx0;
    #pragma unroll
    for (int kf = 0; kf < 4; kf++) nx0 = __builtin_amdgcn_mfma_f32_16x16x32_bf16(Axn[kf], Wi[0][kf], nx0, 0,0,0);
    #pragma unroll
    for (int kf = 0; kf < 4; kf++) nx1 = __builtin_amdgcn_mfma_f32_16x16x32_bf16(Axn[kf], Wi[1][kf], nx1, 0,0,0);
    #pragma unroll
    for (int kf = 0; kf < 4; kf++) nx2 = __builtin_amdgcn_mfma_f32_16x16x32_bf16(Axn[kf], Wi[2][kf], nx2, 0,0,0);

    // commit prefetched x(s+2) into the dead buffer; issue prefetch of x(s+3)
    *(uint2*)&xbuf[pin][xrow][xc4] = make_uint2(cvt_pk_bf16(xr.x, xr.y), cvt_pk_bf16(xr.z, xr.w));
    {
      int t3 = (s + 3 < tc ? s + 3 : tc - 1);
      xr = ((const float4*)(x + ((size_t)t3 * 1024 + b0) * 128))[tid];
    }

    // x-side gate constants for THIS step (cx computed one step ago)
    float cr[4], cz[4], cn[4];
    #pragma unroll
    for (int r = 0; r < 4; r++) { cr[r] = cx0[r] + br; cz[r] = cx1[r] + bz; cn[r] = cx2[r] + bin; }

    // gates: shared-rcp sigmoid pair + exp-based tanh
    float hnv[4];
    #pragma unroll
    for (int r = 0; r < 4; r++) {
      float er = __expf(-(rh[r] + cr[r]));
      float ez = __expf(-(zh[r] + cz[r]));
      float pr = 1.0f + er, pz = 1.0f + ez;
      float inv = __builtin_amdgcn_rcpf(pr * pz);
      float rr = pz * inv;                  // = 1/(1+er)
      float zz = pr * inv;                  // = 1/(1+ez)
      float y  = cn[r] + rr * (nh[r] + bnh);
      float em = __expf(-2.0f * y);
      float nn = 2.0f * __builtin_amdgcn_rcpf(1.0f + em) - 1.0f;   // tanh(y)
      hnv[r] = nn + zz * (hold[r] - nn);
      hold[r] = hnv[r];
    }
    unsigned int p01 = cvt_pk_bf16(hnv[0], hnv[1]);
    unsigned int p23 = cvt_pk_bf16(hnv[2], hnv[3]);
    unsigned short h0 = (unsigned short)p01, h1 = (unsigned short)(p01 >> 16);
    unsigned short h2 = (unsigned short)p23, h3 = (unsigned short)(p23 >> 16);
    hbuf[pout][q * 4 + 0][col] = h0;
    hbuf[pout][q * 4 + 1][col] = h1;
    hbuf[pout][q * 4 + 2][col] = h2;
    hbuf[pout][q * 4 + 3][col] = h3;
    opq[0]   = h0;
    opq[128] = h1;
    opq[256] = h2;
    opq[384] = h3;

    cx0 = nx0; cx1 = nx1; cx2 = nx2;
    opq += 131072;                          // advance one timestep (1024*128)
    LDS_BARRIER();
  };

  for (int s = 0; s + 1 < tc; s += 2) { step(s, 0, 1); step(s + 1, 1, 0); }
}

// ---------------- K2: barrier-free per-wave score ----------------
// grid 3200 x 256 thr (4 waves). Wave = one 16-row tile of the 204800x128x128x2
// GEMM-reduction. Rows n = tile*16 + l15 are consecutive (t = n>>10, b = n&1023;
// 1024%16==0 so a tile never crosses t). A-frags in regs once; 8 col-strips with
// B-frags from bf16 a12 (identical across waves -> L1-hot). Per-lane psum over
// strips; ONE 4-shfl reduce per tile. No LDS, no syncthreads.
__global__ __launch_bounds__(256) void k_score2(
    const unsigned short* __restrict__ hl, const unsigned short* __restrict__ hg,
    const unsigned short* __restrict__ a12, const float* __restrict__ v1,
    float* __restrict__ score)
{
  int tid = threadIdx.x;
  int wv = tid >> 6, L = tid & 63, l15 = L & 15, q = L >> 4;
  int tile = blockIdx.x * 4 + wv;           // 0..12799
  int n0 = tile * 16;                       // first row of tile
  int t = n0 >> 10;
  int b = n0 & 1023;                        // rows n0..n0+15 -> b..b+15, same t

  // A-fragments: 16 rows x K=128, both matrices (32 VGPR)
  const unsigned short* rowL = hl + ((size_t)n0 + l15) * 128 + q * 8;
  const unsigned short* rowG = hg + ((size_t)n0 + l15) * 128 + q * 8;
  short8 Al[4], Ag[4];
  #pragma unroll
  for (int kf = 0; kf < 4; kf++) {
    Al[kf] = *(const short8*)(rowL + kf * 32);
    Ag[kf] = *(const short8*)(rowG + kf * 32);
  }
  // v1 values for this lane's column in each strip
  float v1v[8];
  #pragma unroll
  for (int st = 0; st < 8; st++) v1v[st] = v1[st * 16 + l15];

  float psum[4] = {0.f, 0.f, 0.f, 0.f};
  #pragma unroll
  for (int st = 0; st < 8; st++) {
    const unsigned short* b1 = a12 + (size_t)(st * 16 + l15) * 128 + q * 8;
    const unsigned short* b2 = b1 + 16384;
    float4v acc = (float4v){0.f, 0.f, 0.f, 0.f};
    #pragma unroll
    for (int kf = 0; kf < 4; kf++)
      acc = __builtin_amdgcn_mfma_f32_16x16x32_bf16(Al[kf], *(const short8*)(b1 + kf * 32), acc, 0,0,0);
    #pragma unroll
    for (int kf = 0; kf < 4; kf++)
      acc = __builtin_amdgcn_mfma_f32_16x16x32_bf16(Ag[kf], *(const short8*)(b2 + kf * 32), acc, 0,0,0);
    #pragma unroll
    for (int r = 0; r < 4; r++) psum[r] += v1v[st] * sigm(acc[r]);
  }
  // reduce over the 16 lanes of each row group; row = q*4 + r -> n = n0 + row
  #pragma unroll
  for (int r = 0; r < 4; r++) {
    float s = psum[r];
    s += __shfl_xor(s, 1, 16);
    s += __shfl_xor(s, 2, 16);
    s += __shfl_xor(s, 4, 16);
    s += __shfl_xor(s, 8, 16);
    if (l15 == 0) score[(size_t)(b + q * 4 + r) * 200 + t] = s;   // layout [b][200]
  }
}

// ---------------- K3: cumsum + capture (proven v4 structure, c=0 init) ----------------
// grid 512, block 256: 2 batch rows/block, thread = (b2, j)
__global__ __launch_bounds__(256) void k_cum(const float* __restrict__ score,
                                             const unsigned short* __restrict__ hl_seq,
                                             const unsigned short* __restrict__ hg_seq,
                                             const int* __restrict__ lengths,
                                             float* __restrict__ out)
{
  __shared__ __align__(16) unsigned short hlL[100 * 256];  // [s_seg][b2*128+j]
  __shared__ float scL[2][100];
  const int tc = 200;
  int tid = threadIdx.x;
  int b2 = tid >> 7, j = tid & 127;
  int b0 = blockIdx.x * 2;
  int b = b0 + b2;
  int base = b2 * 128 + j;

  float c = 0.0f;
  int cap0 = lengths[b] - 4;                // capture window [cap0, cap0+3] in [0,196]

  float hgv[4];
  #pragma unroll
  for (int d = 0; d < 4; d++)
    hgv[d] = bf2f(hg_seq[((size_t)(cap0 + d) * 1024 + b) * 128 + j]);

  for (int seg = 0; seg < tc; seg += 100) {
    __syncthreads();                         // protect LDS reuse across segments
    // stage hl rows [seg, seg+100) : coalesced short8
    for (int f8 = tid; f8 < 100 * 32; f8 += 256) {
      int sl = f8 >> 5, r8 = f8 & 31;
      *(short8*)&hlL[(size_t)f8 * 8] =
          *(const short8*)(hl_seq + ((size_t)(seg + sl) * 1024 + b0) * 128 + r8 * 8);
    }
    // stage score rows (contiguous per b: layout [b][200])
    for (int i = tid; i < 200; i += 256) {
      int bb = (i >= 100) ? 1 : 0;
      int sl = i - bb * 100;
      scL[bb][sl] = score[(size_t)(b0 + bb) * 200 + seg + sl];
    }
    __syncthreads();

    for (int sl = 0; sl < 100; sl += 5) {
      float h[5], sc[5];
      #pragma unroll
      for (int k = 0; k < 5; k++) {
        h[k] = bf2f(hlL[(size_t)(sl + k) * 256 + base]);
        sc[k] = scL[b2][sl + k];
      }
      #pragma unroll
      for (int k = 0; k < 5; k++) {
        c += sc[k] * h[k];
        int d = (seg + sl + k) - cap0;
        if ((unsigned)d < 4u)
          out[((size_t)b * 4 + d) * 128 + j] = c + hgv[d];
      }
    }
  }
}

// ---------------- launch ----------------
extern "C" void kernel_launch(void* const* d_in, const int* in_sizes, int n_in,
                              void* d_out, int out_size, void* d_ws, size_t ws_size,
                              hipStream_t stream)
{
  const float* x     = (const float*)d_in[0];
  const int* lengths = (const int*)d_in[1];
  const float* Wih_g = (const float*)d_in[2];
  const float* Whh_g = (const float*)d_in[3];
  const float* bih_g = (const float*)d_in[4];
  const float* bhh_g = (const float*)d_in[5];
  const float* Wih_l = (const float*)d_in[6];
  const float* Whh_l = (const float*)d_in[7];
  const float* bih_l = (const float*)d_in[8];
  const float* bhh_l = (const float*)d_in[9];
  const float* A1    = (const float*)d_in[10];
  const float* A2    = (const float*)d_in[11];
  const float* v1    = (const float*)d_in[12];
  float* out = (float*)d_out;

  char* wsb = (char*)d_ws;
  size_t o = 0;
  unsigned short* a12 = (unsigned short*)(wsb + o); o += 65536;
  unsigned short* hl  = (unsigned short*)(wsb + o); o += (size_t)200 * 1024 * 128 * 2;
  unsigned short* hg  = (unsigned short*)(wsb + o); o += (size_t)200 * 1024 * 128 * 2;
  float* score        = (float*)(wsb + o);          o += (size_t)1024 * 200 * 4;
  if (o > ws_size) return;

  k_build<<<64, 512, 0, stream>>>(A1, A2, a12);
  k_scan<<<128, 512, 0, stream>>>(x, Wih_g, Whh_g, bih_g, bhh_g,
                                  Wih_l, Whh_l, bih_l, bhh_l, hl, hg);
  k_score2<<<3200, 256, 0, stream>>>(hl, hg, a12, v1, score);
  k_cum<<<512, 256, 0, stream>>>(score, hl, hg, lengths, out);
}